// Round 14
// baseline (182.213 us; speedup 1.0000x reference)
//
#include <hip/hip_runtime.h>
#include <cstdint>
#include <cstddef>

typedef __bf16 bf16x8 __attribute__((ext_vector_type(8)));
typedef short  s16x8  __attribute__((ext_vector_type(8)));
typedef float  f32x4  __attribute__((ext_vector_type(4)));
typedef unsigned int u32x4 __attribute__((ext_vector_type(4)));
typedef unsigned int u32x2 __attribute__((ext_vector_type(2)));

#define MFMA16(a, b, c) __builtin_amdgcn_mfma_f32_16x16x32_bf16((a), (b), (c), 0, 0, 0)

typedef __attribute__((address_space(3))) unsigned int       lds_uint;
typedef const __attribute__((address_space(1))) unsigned int glb_uint;

// async global->LDS, 16B per lane; LDS dest = uniform base + lane*16
static __device__ __forceinline__ void gload_lds16(const void* g, void* l) {
  __builtin_amdgcn_global_load_lds((glb_uint*)g, (lds_uint*)l, 16, 0, 0);
}

static __device__ __forceinline__ unsigned short f2bf(float f) {
  unsigned u = __builtin_bit_cast(unsigned, f);
  unsigned r = u + 0x7FFFu + ((u >> 16) & 1u);
  return (unsigned short)(r >> 16);
}
static __device__ __forceinline__ float bf2f(unsigned short u) {
  unsigned x = ((unsigned)u) << 16;
  return __builtin_bit_cast(float, x);
}
static __device__ __forceinline__ float fast_tanh(float x) {
  float e = __expf(2.f * x);
  return 1.f - 2.f / (e + 1.f);
}
static __device__ __forceinline__ unsigned cvt_pk_bf16(float lo, float hi) {
  unsigned r;
  asm("v_cvt_pk_bf16_f32 %0, %1, %2" : "=v"(r) : "v"(lo), "v"(hi));
  return r;
}
// unpack 8 bf16 from u32x4, y = tanh(mul * x), repack
static __device__ __forceinline__ u32x4 tanh8(u32x4 q, float mul) {
  u32x4 o;
#pragma unroll
  for (int j = 0; j < 4; ++j) {
    float lo = bf2f((unsigned short)(q[j] & 0xffffu)) * mul;
    float hi = bf2f((unsigned short)(q[j] >> 16)) * mul;
    o[j] = cvt_pk_bf16(fast_tanh(lo), fast_tanh(hi));
  }
  return o;
}

// ---------- elementwise fp32 -> bf16 (x4 vectorized) ----------
__global__ void k_f32_to_bf16(const float* __restrict__ src,
                              unsigned short* __restrict__ dst, int n4) {
  int i = blockIdx.x * blockDim.x + threadIdx.x;
  if (i >= n4) return;
  float4 v = reinterpret_cast<const float4*>(src)[i];
  ushort4 o;
  o.x = f2bf(v.x); o.y = f2bf(v.y); o.z = f2bf(v.z); o.w = f2bf(v.w);
  reinterpret_cast<ushort4*>(dst)[i] = o;
}

// ---------- fused transpose of 4 fp32 1024x1024 weights -> bf16 [N][K] ----------
__global__ void k_transpose4_to_bf16(const float* __restrict__ s0,
                                     const float* __restrict__ s1,
                                     const float* __restrict__ s2,
                                     const float* __restrict__ s3,
                                     unsigned short* __restrict__ dstBase) {
  __shared__ float t[32][33];
  const int z = blockIdx.z;
  const float* src = (z == 0) ? s0 : (z == 1) ? s1 : (z == 2) ? s2 : s3;
  unsigned short* dst = dstBase + (size_t)z * 1048576;
  int c0 = blockIdx.x * 32, r0 = blockIdx.y * 32;
  int tx = threadIdx.x, ty = threadIdx.y;
#pragma unroll
  for (int i = 0; i < 4; ++i)
    t[ty + i * 8][tx] = src[(size_t)(r0 + ty + i * 8) * 1024 + c0 + tx];
  __syncthreads();
#pragma unroll
  for (int i = 0; i < 4; ++i)
    dst[(size_t)(c0 + ty + i * 8) * 1024 + r0 + tx] = f2bf(t[tx][ty + i * 8]);
}

// ---------- 128x128 tile GEMM, 2-phase (prefetch-next dbuf, 1 barrier/K-tile) ----------
__global__ __launch_bounds__(256) void k_gemm_op(
    const unsigned short* __restrict__ A, const unsigned short* __restrict__ Bt,
    int M, int N, int K,
    float* __restrict__ Cout, const float* __restrict__ bias) {
  __shared__ __align__(16) unsigned short Al[2][128 * 64];
  __shared__ __align__(16) unsigned short Bl[2][128 * 64];
  const int tid = threadIdx.x;
  const int lane = tid & 63, w = tid >> 6;
  const int wm = w >> 1, wn = w & 1;
  const int l15 = lane & 15, l4 = lane >> 4;
  const int m0 = blockIdx.y * 128, n0 = blockIdx.x * 128;
  const int NT = K >> 6;

  const int srow = lane >> 3;
  const int schunk = (lane & 7) ^ srow;
  const unsigned short* Ag = A + (size_t)(m0 + (w << 5) + srow) * K + (schunk << 3);
  const unsigned short* Bg = Bt + (size_t)(n0 + (w << 5) + srow) * K + (schunk << 3);

  auto stage = [&](int slot, int t) {
    unsigned short* Alw = &Al[slot][0] + (w << 5) * 64;
    unsigned short* Blw = &Bl[slot][0] + (w << 5) * 64;
#pragma unroll
    for (int p = 0; p < 4; ++p) {
      gload_lds16(Ag + (size_t)(p * 8) * K + t * 64, Alw + p * 8 * 64);
      gload_lds16(Bg + (size_t)(p * 8) * K + t * 64, Blw + p * 8 * 64);
    }
  };

  const f32x4 zero4 = {0.f, 0.f, 0.f, 0.f};
  f32x4 acc[4][4];
#pragma unroll
  for (int i = 0; i < 4; ++i)
#pragma unroll
    for (int j = 0; j < 4; ++j) acc[i][j] = zero4;

  stage(0, 0);
  __syncthreads();

  for (int t = 0; t < NT; ++t) {
    const int s = t & 1;
    const int tn = (t + 1 < NT) ? t + 1 : NT - 1;  // tail: dead-slot reload
    stage(s ^ 1, tn);
    const char* As = (const char*)&Al[s][0];
    const char* Bs = (const char*)&Bl[s][0];
#pragma unroll
    for (int c = 0; c < 2; ++c) {
      bf16x8 af[4], bfr[4];
#pragma unroll
      for (int i = 0; i < 4; ++i) {
        int ra = wm * 64 + i * 16 + l15;
        af[i] = *reinterpret_cast<const bf16x8*>(
            As + ra * 128 + ((c * 64 + l4 * 16) ^ ((ra & 7) << 4)));
        int rb = wn * 64 + i * 16 + l15;
        bfr[i] = *reinterpret_cast<const bf16x8*>(
            Bs + rb * 128 + ((c * 64 + l4 * 16) ^ ((rb & 7) << 4)));
      }
      __builtin_amdgcn_s_setprio(1);
#pragma unroll
      for (int i = 0; i < 4; ++i)
#pragma unroll
        for (int j = 0; j < 4; ++j) acc[i][j] = MFMA16(af[i], bfr[j], acc[i][j]);
      __builtin_amdgcn_s_setprio(0);
    }
    __syncthreads();  // drains prefetch vmcnt; WAR-protects both slots
  }

#pragma unroll
  for (int i = 0; i < 4; ++i)
#pragma unroll
    for (int j = 0; j < 4; ++j)
#pragma unroll
      for (int r = 0; r < 4; ++r) {
        int mrow = m0 + wm * 64 + i * 16 + l4 * 4 + r;
        int ncol = n0 + wn * 64 + j * 16 + l15;
        Cout[(size_t)mrow * N + ncol] = acc[i][j][r] + bias[ncol];
      }
}

// ---------- 256x256-tile 2-phase bf16 GEMM (QKV projection) ----------
__global__ __launch_bounds__(512, 2) void k_gemm256_qkv(
    const unsigned short* __restrict__ A, const unsigned short* __restrict__ Bt,
    int M, int N, int K,
    const float* __restrict__ bq, const float* __restrict__ bk,
    const float* __restrict__ bv,
    unsigned short* __restrict__ Qa, unsigned short* __restrict__ Ka,
    unsigned short* __restrict__ Vt, unsigned short* __restrict__ Qn) {
  __shared__ __align__(16) unsigned short SLDS[4 * 256 * 64];  // 128 KB
  const int tid = threadIdx.x;
  const int lane = tid & 63;
  const int w = tid >> 6, wm = w >> 2, wn = w & 3;
  const int l15 = lane & 15, l4 = lane >> 4;
  const int nbx = N >> 8;
  const int bid = (int)blockIdx.x;
  const int lin = (bid & 7) * ((int)gridDim.x >> 3) + (bid >> 3);  // XCD swizzle
  const int m0 = (lin / nbx) << 8, n0 = (lin % nbx) << 8;
  const int NT = K >> 6;

  const int strow = tid >> 3, stchunk = tid & 7;
  const int schunk = stchunk ^ (strow & 7);  // pre-swizzled source chunk

  auto stage = [&](int slot, int kt) {
    unsigned short* Ad = SLDS + slot * 16384;
    unsigned short* Bd = SLDS + (2 + slot) * 16384;
#pragma unroll
    for (int i = 0; i < 4; ++i) {
      int row = i * 64 + strow;
      gload_lds16(A + (size_t)(m0 + row) * K + kt * 64 + schunk * 8,
                  Ad + row * 64 + stchunk * 8);
      gload_lds16(Bt + (size_t)(n0 + row) * K + kt * 64 + schunk * 8,
                  Bd + row * 64 + stchunk * 8);
    }
  };

  const f32x4 zero4 = {0.f, 0.f, 0.f, 0.f};
  f32x4 acc[8][4];
#pragma unroll
  for (int i = 0; i < 8; ++i)
#pragma unroll
    for (int j = 0; j < 4; ++j) acc[i][j] = zero4;

  stage(0, 0);
  __syncthreads();

  bf16x8 af[4][2], bf0[2][2], bf1[2][2];

  for (int kt = 0; kt < NT; ++kt) {
    const int s = kt & 1;
    const char* As = (const char*)(SLDS + s * 16384);
    const char* Bs = (const char*)(SLDS + (2 + s) * 16384);
    const int kp1 = (kt + 1 < NT) ? kt + 1 : NT - 1;

    stage(s ^ 1, kp1);  // prefetch next tile; drained by this iter's syncthreads

    // quadrant (mh0, nh0)
#pragma unroll
    for (int i = 0; i < 4; ++i) {
      const int ra = wm * 128 + i * 16 + l15;
#pragma unroll
      for (int kk = 0; kk < 2; ++kk)
        af[i][kk] = *(const bf16x8*)(As + ra * 128 + (((kk * 4 + l4) ^ (ra & 7)) << 4));
    }
#pragma unroll
    for (int j = 0; j < 2; ++j) {
      const int rb = wn * 64 + j * 16 + l15;
#pragma unroll
      for (int kk = 0; kk < 2; ++kk)
        bf0[j][kk] = *(const bf16x8*)(Bs + rb * 128 + (((kk * 4 + l4) ^ (rb & 7)) << 4));
    }
    __builtin_amdgcn_s_setprio(1);
#pragma unroll
    for (int i = 0; i < 4; ++i)
#pragma unroll
      for (int j = 0; j < 2; ++j)
#pragma unroll
        for (int kk = 0; kk < 2; ++kk)
          acc[i][j] = MFMA16(af[i][kk], bf0[j][kk], acc[i][j]);
    __builtin_amdgcn_s_setprio(0);

    // quadrant (mh0, nh1)
#pragma unroll
    for (int j = 0; j < 2; ++j) {
      const int rb = wn * 64 + (2 + j) * 16 + l15;
#pragma unroll
      for (int kk = 0; kk < 2; ++kk)
        bf1[j][kk] = *(const bf16x8*)(Bs + rb * 128 + (((kk * 4 + l4) ^ (rb & 7)) << 4));
    }
    __builtin_amdgcn_s_setprio(1);
#pragma unroll
    for (int i = 0; i < 4; ++i)
#pragma unroll
      for (int j = 0; j < 2; ++j)
#pragma unroll
        for (int kk = 0; kk < 2; ++kk)
          acc[i][2 + j] = MFMA16(af[i][kk], bf1[j][kk], acc[i][2 + j]);
    __builtin_amdgcn_s_setprio(0);

    // quadrant (mh1, nh1)
#pragma unroll
    for (int i = 0; i < 4; ++i) {
      const int ra = wm * 128 + (4 + i) * 16 + l15;
#pragma unroll
      for (int kk = 0; kk < 2; ++kk)
        af[i][kk] = *(const bf16x8*)(As + ra * 128 + (((kk * 4 + l4) ^ (ra & 7)) << 4));
    }
    __builtin_amdgcn_s_setprio(1);
#pragma unroll
    for (int i = 0; i < 4; ++i)
#pragma unroll
      for (int j = 0; j < 2; ++j)
#pragma unroll
        for (int kk = 0; kk < 2; ++kk)
          acc[4 + i][2 + j] = MFMA16(af[i][kk], bf1[j][kk], acc[4 + i][2 + j]);

    // quadrant (mh1, nh0) — register-only
#pragma unroll
    for (int i = 0; i < 4; ++i)
#pragma unroll
      for (int j = 0; j < 2; ++j)
#pragma unroll
        for (int kk = 0; kk < 2; ++kk)
          acc[4 + i][j] = MFMA16(af[i][kk], bf0[j][kk], acc[4 + i][j]);
    __builtin_amdgcn_s_setprio(0);

    __syncthreads();  // single sync: drains prefetch, WAR-protects both slots
  }
  // loop's final __syncthreads: all LDS reads + LDS-DMA writes drained -> LDS free

  // ---- coalesced epilogue via per-wave LDS restage (16 KB/wave) ----
  char* wbuf = reinterpret_cast<char*>(SLDS) + w * 16384;
  const int proj = n0 >> 10;                 // block-uniform (256 | 1024)
  const int nn0 = (n0 + wn * 64) & 1023;     // wave = one head
  const int hh = nn0 >> 6;
  const int mbase = m0 + wm * 128;
  const int bb = mbase >> 11;
  const float* bias = (proj == 0) ? bq : (proj == 1) ? bk : bv;
  float bcol[4];
#pragma unroll
  for (int nf = 0; nf < 4; ++nf) bcol[nf] = bias[nn0 + nf * 16 + l15];

  if (proj == 2) {
    // V: stage TRANSPOSED [d][token], XOR-swizzled 16B chunks
#pragma unroll
    for (int mf = 0; mf < 8; ++mf) {
#pragma unroll
      for (int nf = 0; nf < 4; ++nf) {
        const int d = nf * 16 + l15;
        const int tok = mf * 16 + l4 * 4;
        u32x2 pk;
        pk[0] = cvt_pk_bf16(acc[mf][nf][0] + bcol[nf], acc[mf][nf][1] + bcol[nf]);
        pk[1] = cvt_pk_bf16(acc[mf][nf][2] + bcol[nf], acc[mf][nf][3] + bcol[nf]);
        *reinterpret_cast<u32x2*>(
            wbuf + d * 256 + (((tok >> 3) ^ (d & 7)) << 4) + (tok & 7) * 2) = pk;
      }
    }
    __syncthreads();
    const size_t vbase = (size_t)(bb * 16 + hh) * 64 * 2048;
#pragma unroll
    for (int dblk = 0; dblk < 8; ++dblk) {
#pragma unroll
      for (int thalf = 0; thalf < 2; ++thalf) {
        const int d = (lane >> 3) + dblk * 8;
        const int tch = (lane & 7) + thalf * 8;
        u32x4 vv = *reinterpret_cast<const u32x4*>(
            wbuf + d * 256 + ((tch ^ (d & 7)) << 4));
        const int sidx = (mbase + tch * 8) & 2047;
        *reinterpret_cast<u32x4*>(Vt + vbase + (size_t)d * 2048 + sidx) = vv;
      }
    }
  } else {
    // Q/K: stage [token][d] (2B writes), read back 16B rows of d
#pragma unroll
    for (int mf = 0; mf < 8; ++mf) {
#pragma unroll
      for (int nf = 0; nf < 4; ++nf) {
        const int d = nf * 16 + l15;
#pragma unroll
        for (int r = 0; r < 4; ++r) {
          float v = acc[mf][nf][r] + bcol[nf];
          if (proj == 0) v *= 0.125f;  // stage q/8 (Q path)
          const int tok = mf * 16 + l4 * 4 + r;
          *reinterpret_cast<unsigned short*>(wbuf + tok * 128 + d * 2) = f2bf(v);
        }
      }
    }
    __syncthreads();
    const size_t t64base = (size_t)(bb * 16 + hh) * 2048;
#pragma unroll
    for (int iter = 0; iter < 16; ++iter) {
      const int tl = (lane >> 3) + iter * 8;
      const int dc = lane & 7;
      u32x4 q8 = *reinterpret_cast<const u32x4*>(wbuf + tl * 128 + dc * 16);
      const size_t t64 = t64base + ((mbase + tl) & 2047);
      if (proj == 0) {
        *reinterpret_cast<u32x4*>(Qa + t64 * 128 + dc * 8) = q8;        // q/8
        u32x4 qn = tanh8(q8, 8.0f);                                     // tanh(q)
        *reinterpret_cast<u32x4*>(Qn + t64 * 64 + dc * 8) = qn;
      } else {
        *reinterpret_cast<u32x4*>(Ka + t64 * 128 + dc * 8) = q8;        // k
        u32x4 kn = tanh8(q8, 1.0f);                                     // tanh(k)
        *reinterpret_cast<u32x4*>(Ka + t64 * 128 + 64 + dc * 8) = kn;
      }
    }
  }
}

// ---------- Qa[:,64:128] = lam * tanh(Q) @ J[h] ----------
__global__ __launch_bounds__(256) void k_qnj(const unsigned short* __restrict__ Qn,
                                             const float* __restrict__ J,
                                             const float* __restrict__ lamPtr,
                                             unsigned short* __restrict__ Qa) {
  __shared__ float Jl[64 * 64];
  __shared__ float Ql[64 * 64];
  int bid = blockIdx.x;
  int bh = bid >> 5, sblk = bid & 31;
  int h = bh & 15;
  int tid = threadIdx.x;
  float lam = lamPtr[0];
  const float4* Jh = reinterpret_cast<const float4*>(J + (size_t)h * 4096);
#pragma unroll
  for (int p = 0; p < 4; ++p)
    reinterpret_cast<float4*>(Jl)[p * 256 + tid] = Jh[p * 256 + tid];
  size_t tok0 = (size_t)bh * 2048 + sblk * 64;
#pragma unroll
  for (int p = 0; p < 2; ++p) {
    int idx = p * 256 + tid;
    s16x8 v = *reinterpret_cast<const s16x8*>(Qn + tok0 * 64 + idx * 8);
#pragma unroll
    for (int j = 0; j < 8; ++j) Ql[idx * 8 + j] = bf2f((unsigned short)v[j]);
  }
  __syncthreads();
  int e = tid & 63, wq = tid >> 6;
#pragma unroll 1
  for (int pass = 0; pass < 16; ++pass) {
    int tok = pass * 4 + wq;
    float a0 = 0.f, a1 = 0.f;
#pragma unroll
    for (int d = 0; d < 64; d += 2) {
      a0 += Ql[tok * 64 + d] * Jl[d * 64 + e];
      a1 += Ql[tok * 64 + d + 1] * Jl[(d + 1) * 64 + e];
    }
    Qa[(tok0 + tok) * 128 + 64 + e] = f2bf(lam * (a0 + a1));
  }
}

// ---------- causal flash attention, augmented d=128, dv=64 ----------
// 32 q-rows/wave (2 subtiles, 2x K/V LDS reuse) + PAIR-BALANCED blocks:
// each block runs q-tiles (15-p) then (p) => exactly 34 steps per block.
// Grid 256 = 8 pairs x 32 bh, 1 block/CU, all CUs finish together.
__global__ __launch_bounds__(256) void k_attn(const unsigned short* __restrict__ Qa,
                                              const unsigned short* __restrict__ Ka,
                                              const unsigned short* __restrict__ Vt,
                                              unsigned short* __restrict__ Ob) {
  constexpr int S = 2048;
  __shared__ __align__(16) unsigned short Klds[2][64 * 128];  // swizzled 256B rows
  __shared__ __align__(16) unsigned short Vtl[2][64 * 64];    // [dv][kv] swizzled

  const int blk = (int)blockIdx.x;
  const int xg = blk & 7, idx = blk >> 3;   // idx 0..31
  const int bh = xg * 4 + (idx & 3);        // 4 heads per XCD for L2 locality
  const int pr = idx >> 2;                  // 0..7 -> pair (15-pr, pr)
  const int b = bh >> 4, h = bh & 15;
  const int tid = threadIdx.x;
  const int lane = tid & 63, w = tid >> 6;
  const int l15 = lane & 15, l4 = lane >> 4;
  const size_t bhS = (size_t)bh * S;
  const unsigned short* Kbase = Ka + bhS * 128;
  const unsigned short* Vbase = Vt + (size_t)bh * 64 * 2048;
  const f32x4 zero4 = {0.f, 0.f, 0.f, 0.f};

  const int rowbase = w * 16 + (lane >> 4);
  const int rb7 = rowbase & 7;
  const int cK0 = (lane & 15) ^ rb7;
  const int cK1 = cK0 ^ 4;
  const int vdvrow = w * 16 + (lane >> 3);
  const int cV = (lane & 7) ^ ((lane >> 3) & 7);

  const int I0 = (l15 + 32 * (l4 & 1)) * 4;
  const int I1 = I0 + 64;
  const bool hi4 = (lane & 32) != 0;

  for (int half = 0; half < 2; ++half) {
    const int qt = half ? pr : (15 - pr);   // long half first
    const int q0 = qt * 128;
    const int NT = 2 * qt + 2;              // kv tiles of 64

    // Q: 2 subtiles x 4 frags, held in registers for this half
    bf16x8 qf[2][4];
#pragma unroll
    for (int qs = 0; qs < 2; ++qs) {
      int qrow = q0 + w * 32 + qs * 16 + l15;
#pragma unroll
      for (int c = 0; c < 4; ++c)
        qf[qs][c] = *reinterpret_cast<const bf16x8*>(Qa + (bhS + qrow) * 128 + c * 32 + l4 * 8);
    }

    f32x4 oacc[2][4];
    float m_[2], lsum[2];
#pragma unroll
    for (int qs = 0; qs < 2; ++qs) {
      m_[qs] = -__builtin_inff(); lsum[qs] = 0.f;
#pragma unroll
      for (int v = 0; v < 4; ++v) oacc[qs][v] = zero4;
    }

    // prologue: stage kt=0 into buf 0 (prev half's final syncthreads protects)
#pragma unroll
    for (int p = 0; p < 4; ++p)
      gload_lds16(Kbase + (size_t)(rowbase + 4 * p) * 128 + ((p & 1) ? cK1 : cK0) * 8,
                  &Klds[0][(w * 16 + p * 4) * 128]);
#pragma unroll
    for (int p = 0; p < 2; ++p)
      gload_lds16(Vbase + (size_t)(vdvrow + 8 * p) * 2048 + cV * 8,
                  &Vtl[0][(w * 16 + p * 8) * 64]);
    __syncthreads();

    for (int kt = 0; kt < NT; ++kt) {
      const int cur = kt & 1;

      if (kt + 1 < NT) {
        const int base = (kt + 1) * 64;
        const int nxt = cur ^ 1;
#pragma unroll
        for (int p = 0; p < 4; ++p)
          gload_lds16(Kbase + (size_t)(base + rowbase + 4 * p) * 128 + ((p & 1) ? cK1 : cK0) * 8,
                      &Klds[nxt][(w * 16 + p * 4) * 128]);
#pragma unroll
        for (int p = 0; p < 2; ++p)
          gload_lds16(Vbase + (size_t)(vdvrow + 8 * p) * 2048 + base + cV * 8,
                      &Vtl[nxt][(w * 16 + p * 8) * 64]);
      }

      // ---- QK^T swapped for BOTH q-subtiles: each kf read feeds 2 MFMAs
      const char* Kl = reinterpret_cast<const char*>(Klds[cur]);
      f32x4 sc[2][4];
      __builtin_amdgcn_s_setprio(1);
#pragma unroll
      for (int fn = 0; fn < 4; ++fn) {
        sc[0][fn] = zero4; sc[1][fn] = zero4;
        const int krow = fn * 16 + l15;
#pragma unroll
        for (int c = 0; c < 4; ++c) {
          bf16x8 kf = *reinterpret_cast<const bf16x8*>(
              Kl + krow * 256 + (((c * 4 + l4) ^ (krow & 7)) << 4));
          sc[0][fn] = MFMA16(kf, qf[0][c], sc[0][fn]);
          sc[1][fn] = MFMA16(kf, qf[1][c], sc[1][fn]);
        }
      }
      __builtin_amdgcn_s_setprio(0);

      // ---- per-subtile: mask + online softmax + pack
      unsigned cp[2][4][2];
#pragma unroll
      for (int qs = 0; qs < 2; ++qs) {
        const int qmin = q0 + w * 32 + qs * 16;
        if (kt * 64 + 63 > qmin) {  // diagonal / masked zone for this subtile
          const int qloc = qmin + l15;
#pragma unroll
          for (int fn = 0; fn < 4; ++fn)
#pragma unroll
            for (int r = 0; r < 4; ++r)
              if (kt * 64 + fn * 16 + l4 * 4 + r > qloc) sc[qs][fn][r] = -__builtin_inff();
        }
        float mx = sc[qs][0][0];
#pragma unroll
        for (int fn = 0; fn < 4; ++fn)
#pragma unroll
          for (int r = 0; r < 4; ++r) mx = fmaxf(mx, sc[qs][fn][r]);
        mx = fmaxf(mx, __shfl_xor(mx, 16));
        mx = fmaxf(mx, __shfl_xor(mx, 32));
        const float mn = fmaxf(m_[qs], mx);
        const float al = __expf(m_[qs] - mn);
        float p_[4][4];
        float rs = 0.f;
#pragma unroll
        for (int fn = 0; fn < 4; ++fn)
#pragma unroll
          for (int r = 0; r < 4; ++r) {
            float e = __expf(sc[qs][fn][r] - mn);
            p_[fn][r] = e;
            rs += e;
          }
        rs += __shfl_xor(rs, 16);
        rs += __shfl_xor(rs, 32);
        lsum[qs] = lsum[qs] * al + rs;
        m_[qs] = mn;
#pragma unroll
        for (int r = 0; r < 4; ++r) {
          float albc = __shfl(al, l4 * 4 + r);
#pragma unroll
          for (int v = 0; v < 4; ++v) oacc[qs][v][r] *= albc;
        }
#pragma unroll
        for (int fn = 0; fn < 4; ++fn) {
          cp[qs][fn][0] = cvt_pk_bf16(p_[fn][0], p_[fn][1]);
          cp[qs][fn][1] = cvt_pk_bf16(p_[fn][2], p_[fn][3]);
        }
      }

      // ---- PV: each vf read feeds 2 MFMAs
      const char* Vl = reinterpret_cast<const char*>(Vtl[cur]);
#pragma unroll
      for (int c2 = 0; c2 < 2; ++c2) {
        bf16x8 pa[2];
#pragma unroll
        for (int qs = 0; qs < 2; ++qs) {
          unsigned a0 = __builtin_amdgcn_ds_bpermute(I0, (int)cp[qs][c2 * 2][0]);
          unsigned b0 = __builtin_amdgcn_ds_bpermute(I0, (int)cp[qs][c2 * 2 + 1][0]);
          unsigned a1 = __builtin_amdgcn_ds_bpermute(I0, (int)cp[qs][c2 * 2][1]);
          unsigned b1 = __builtin_amdgcn_ds_bpermute(I0, (int)cp[qs][c2 * 2 + 1][1]);
          unsigned a2 = __builtin_amdgcn_ds_bpermute(I1, (int)cp[qs][c2 * 2][0]);
          unsigned b2 = __builtin_amdgcn_ds_bpermute(I1, (int)cp[qs][c2 * 2 + 1][0]);
          unsigned a3 = __builtin_amdgcn_ds_bpermute(I1, (int)cp[qs][c2 * 2][1]);
          unsigned b3 = __builtin_amdgcn_ds_bpermute(I1, (int)cp[qs][c2 * 2 + 1][1]);
          u32x4 pw = {hi4 ? b0 : a0, hi4 ? b1 : a1, hi4 ? b2 : a2, hi4 ? b3 : a3};
          pa[qs] = __builtin_bit_cast(bf16x8, pw);
        }
        __builtin_amdgcn_s_setprio(1);
#pragma unroll
        for (int v = 0; v < 4; ++v) {
          const int dvrow = v * 16 + l15;
          bf16x8 vf = *reinterpret_cast<const bf16x8*>(
              Vl + dvrow * 128 + (((c2 * 4 + l4) ^ (dvrow & 7)) << 4));
          oacc[0][v] = MFMA16(pa[0], vf, oacc[0][v]);
          oacc[1][v] = MFMA16(pa[1], vf, oacc[1][v]);
        }
        __builtin_amdgcn_s_setprio(0);
      }

      __syncthreads();
    }

    // ---- epilogue: rows q0 + w*32 + qs*16 + l4*4 + r
#pragma unroll
    for (int qs = 0; qs < 2; ++qs) {
      float lbc[4];
#pragma unroll
      for (int r = 0; r < 4; ++r) lbc[r] = __shfl(lsum[qs], l4 * 4 + r);
#pragma unroll
      for (int v = 0; v < 4; ++v) {
#pragma unroll
        for (int r = 0; r < 4; ++r) {
          int row = q0 + w * 32 + qs * 16 + l4 * 4 + r;
          float o = oacc[qs][v][r] / lbc[r];
          Ob[((size_t)b * S + row) * 1024 + h * 64 + v * 16 + l15] = f2bf(o);
        }
      }
    }
  }
}

extern "C" void kernel_launch(void* const* d_in, const int* in_sizes, int n_in,
                              void* d_out, int out_size, void* d_ws, size_t ws_size,
                              hipStream_t stream) {
  const float* x   = (const float*)d_in[0];
  const float* Wq  = (const float*)d_in[1];
  const float* bq  = (const float*)d_in[2];
  const float* Wk  = (const float*)d_in[3];
  const float* bk  = (const float*)d_in[4];
  const float* Wv  = (const float*)d_in[5];
  const float* bv  = (const float*)d_in[6];
  const float* Wo  = (const float*)d_in[7];
  const float* bo  = (const float*)d_in[8];
  const float* J   = (const float*)d_in[9];
  const float* lam = (const float*)d_in[10];
  float* out = (float*)d_out;

  char* ws = (char*)d_ws;
  unsigned short* xb     = (unsigned short*)(ws);              //  8,388,608 B
  unsigned short* Wt_qkv = (unsigned short*)(ws + 8388608);    //  6,291,456 B
  unsigned short* Wt_o   = (unsigned short*)(ws + 14680064);   //  2,097,152 B
  unsigned short* Qa     = (unsigned short*)(ws + 16777216);   // 16,777,216 B
  unsigned short* Ka     = (unsigned short*)(ws + 33554432);   // 16,777,216 B
  unsigned short* Vt     = (unsigned short*)(ws + 50331648);   //  8,388,608 B
  unsigned short* Qn     = (unsigned short*)(ws + 58720256);   //  8,388,608 B
  unsigned short* Ob     = (unsigned short*)(ws + 67108864);   //  8,388,608 B

  // 1) x -> bf16
  k_f32_to_bf16<<<4096, 256, 0, stream>>>(x, xb, 1048576);

  // 2) all 4 weights -> transposed bf16 (Wt_qkv and Wt_o are adjacent in ws)
  k_transpose4_to_bf16<<<dim3(32, 32, 4), dim3(32, 8), 0, stream>>>(
      Wq, Wk, Wv, Wo, Wt_qkv);

  // 3) fused QKV projection, 256^2 2-phase + coalesced LDS-restaged epilogue
  k_gemm256_qkv<<<192, 512, 0, stream>>>(xb, Wt_qkv, 4096, 3072, 1024,
      bq, bk, bv, Qa, Ka, Vt, Qn);

  // 4) Qa[:,64:128] = lam * tanh(Q) @ J[h]
  k_qnj<<<1024, 256, 0, stream>>>(Qn, J, lam, Qa);

  // 5) causal flash attention (256 pair-balanced blocks: 8 pairs x 32 bh)
  k_attn<<<256, 256, 0, stream>>>(Qa, Ka, Vt, Ob);

  // 6) output projection + bias -> fp32 d_out (2-phase 128^2)
  k_gemm_op<<<dim3(8, 32), 256, 0, stream>>>(Ob, Wt_o, 4096, 1024, 1024,
      out, bo);
}

// Round 15
// 158.476 us; speedup vs baseline: 1.1498x; 1.1498x over previous
//
#include <hip/hip_runtime.h>
#include <cstdint>
#include <cstddef>

typedef __bf16 bf16x8 __attribute__((ext_vector_type(8)));
typedef short  s16x8  __attribute__((ext_vector_type(8)));
typedef float  f32x4  __attribute__((ext_vector_type(4)));
typedef unsigned int u32x4 __attribute__((ext_vector_type(4)));
typedef unsigned int u32x2 __attribute__((ext_vector_type(2)));

#define MFMA16(a, b, c) __builtin_amdgcn_mfma_f32_16x16x32_bf16((a), (b), (c), 0, 0, 0)

typedef __attribute__((address_space(3))) unsigned int       lds_uint;
typedef const __attribute__((address_space(1))) unsigned int glb_uint;

// async global->LDS, 16B per lane; LDS dest = uniform base + lane*16
static __device__ __forceinline__ void gload_lds16(const void* g, void* l) {
  __builtin_amdgcn_global_load_lds((glb_uint*)g, (lds_uint*)l, 16, 0, 0);
}

static __device__ __forceinline__ unsigned short f2bf(float f) {
  unsigned u = __builtin_bit_cast(unsigned, f);
  unsigned r = u + 0x7FFFu + ((u >> 16) & 1u);
  return (unsigned short)(r >> 16);
}
static __device__ __forceinline__ float bf2f(unsigned short u) {
  unsigned x = ((unsigned)u) << 16;
  return __builtin_bit_cast(float, x);
}
static __device__ __forceinline__ float fast_tanh(float x) {
  float e = __expf(2.f * x);
  return 1.f - 2.f / (e + 1.f);
}
static __device__ __forceinline__ unsigned cvt_pk_bf16(float lo, float hi) {
  unsigned r;
  asm("v_cvt_pk_bf16_f32 %0, %1, %2" : "=v"(r) : "v"(lo), "v"(hi));
  return r;
}
// raw 2^x (v_exp_f32); s_nop guards the trans-op read hazard
static __device__ __forceinline__ float exp2_(float x) {
  float r;
  asm("v_exp_f32 %0, %1\n\ts_nop 0" : "=v"(r) : "v"(x));
  return r;
}
// unpack 8 bf16 from u32x4, y = tanh(mul * x), repack
static __device__ __forceinline__ u32x4 tanh8(u32x4 q, float mul) {
  u32x4 o;
#pragma unroll
  for (int j = 0; j < 4; ++j) {
    float lo = bf2f((unsigned short)(q[j] & 0xffffu)) * mul;
    float hi = bf2f((unsigned short)(q[j] >> 16)) * mul;
    o[j] = cvt_pk_bf16(fast_tanh(lo), fast_tanh(hi));
  }
  return o;
}

// ---------- elementwise fp32 -> bf16 (x4 vectorized) ----------
__global__ void k_f32_to_bf16(const float* __restrict__ src,
                              unsigned short* __restrict__ dst, int n4) {
  int i = blockIdx.x * blockDim.x + threadIdx.x;
  if (i >= n4) return;
  float4 v = reinterpret_cast<const float4*>(src)[i];
  ushort4 o;
  o.x = f2bf(v.x); o.y = f2bf(v.y); o.z = f2bf(v.z); o.w = f2bf(v.w);
  reinterpret_cast<ushort4*>(dst)[i] = o;
}

// ---------- fused transpose of 4 fp32 1024x1024 weights -> bf16 [N][K] ----------
__global__ void k_transpose4_to_bf16(const float* __restrict__ s0,
                                     const float* __restrict__ s1,
                                     const float* __restrict__ s2,
                                     const float* __restrict__ s3,
                                     unsigned short* __restrict__ dstBase) {
  __shared__ float t[32][33];
  const int z = blockIdx.z;
  const float* src = (z == 0) ? s0 : (z == 1) ? s1 : (z == 2) ? s2 : s3;
  unsigned short* dst = dstBase + (size_t)z * 1048576;
  int c0 = blockIdx.x * 32, r0 = blockIdx.y * 32;
  int tx = threadIdx.x, ty = threadIdx.y;
#pragma unroll
  for (int i = 0; i < 4; ++i)
    t[ty + i * 8][tx] = src[(size_t)(r0 + ty + i * 8) * 1024 + c0 + tx];
  __syncthreads();
#pragma unroll
  for (int i = 0; i < 4; ++i)
    dst[(size_t)(c0 + ty + i * 8) * 1024 + r0 + tx] = f2bf(t[tx][ty + i * 8]);
}

// ---------- 128x128 tile GEMM, 2-phase (prefetch-next dbuf, 1 barrier/K-tile) ----------
__global__ __launch_bounds__(256) void k_gemm_op(
    const unsigned short* __restrict__ A, const unsigned short* __restrict__ Bt,
    int M, int N, int K,
    float* __restrict__ Cout, const float* __restrict__ bias) {
  __shared__ __align__(16) unsigned short Al[2][128 * 64];
  __shared__ __align__(16) unsigned short Bl[2][128 * 64];
  const int tid = threadIdx.x;
  const int lane = tid & 63, w = tid >> 6;
  const int wm = w >> 1, wn = w & 1;
  const int l15 = lane & 15, l4 = lane >> 4;
  const int m0 = blockIdx.y * 128, n0 = blockIdx.x * 128;
  const int NT = K >> 6;

  const int srow = lane >> 3;
  const int schunk = (lane & 7) ^ srow;
  const unsigned short* Ag = A + (size_t)(m0 + (w << 5) + srow) * K + (schunk << 3);
  const unsigned short* Bg = Bt + (size_t)(n0 + (w << 5) + srow) * K + (schunk << 3);

  auto stage = [&](int slot, int t) {
    unsigned short* Alw = &Al[slot][0] + (w << 5) * 64;
    unsigned short* Blw = &Bl[slot][0] + (w << 5) * 64;
#pragma unroll
    for (int p = 0; p < 4; ++p) {
      gload_lds16(Ag + (size_t)(p * 8) * K + t * 64, Alw + p * 8 * 64);
      gload_lds16(Bg + (size_t)(p * 8) * K + t * 64, Blw + p * 8 * 64);
    }
  };

  const f32x4 zero4 = {0.f, 0.f, 0.f, 0.f};
  f32x4 acc[4][4];
#pragma unroll
  for (int i = 0; i < 4; ++i)
#pragma unroll
    for (int j = 0; j < 4; ++j) acc[i][j] = zero4;

  stage(0, 0);
  __syncthreads();

  for (int t = 0; t < NT; ++t) {
    const int s = t & 1;
    const int tn = (t + 1 < NT) ? t + 1 : NT - 1;  // tail: dead-slot reload
    stage(s ^ 1, tn);
    const char* As = (const char*)&Al[s][0];
    const char* Bs = (const char*)&Bl[s][0];
#pragma unroll
    for (int c = 0; c < 2; ++c) {
      bf16x8 af[4], bfr[4];
#pragma unroll
      for (int i = 0; i < 4; ++i) {
        int ra = wm * 64 + i * 16 + l15;
        af[i] = *reinterpret_cast<const bf16x8*>(
            As + ra * 128 + ((c * 64 + l4 * 16) ^ ((ra & 7) << 4)));
        int rb = wn * 64 + i * 16 + l15;
        bfr[i] = *reinterpret_cast<const bf16x8*>(
            Bs + rb * 128 + ((c * 64 + l4 * 16) ^ ((rb & 7) << 4)));
      }
      __builtin_amdgcn_s_setprio(1);
#pragma unroll
      for (int i = 0; i < 4; ++i)
#pragma unroll
        for (int j = 0; j < 4; ++j) acc[i][j] = MFMA16(af[i], bfr[j], acc[i][j]);
      __builtin_amdgcn_s_setprio(0);
    }
    __syncthreads();  // drains prefetch vmcnt; WAR-protects both slots
  }

#pragma unroll
  for (int i = 0; i < 4; ++i)
#pragma unroll
    for (int j = 0; j < 4; ++j)
#pragma unroll
      for (int r = 0; r < 4; ++r) {
        int mrow = m0 + wm * 64 + i * 16 + l4 * 4 + r;
        int ncol = n0 + wn * 64 + j * 16 + l15;
        Cout[(size_t)mrow * N + ncol] = acc[i][j][r] + bias[ncol];
      }
}

// ---------- 256x256-tile 2-phase bf16 GEMM (QKV projection) ----------
__global__ __launch_bounds__(512, 2) void k_gemm256_qkv(
    const unsigned short* __restrict__ A, const unsigned short* __restrict__ Bt,
    int M, int N, int K,
    const float* __restrict__ bq, const float* __restrict__ bk,
    const float* __restrict__ bv,
    unsigned short* __restrict__ Qa, unsigned short* __restrict__ Ka,
    unsigned short* __restrict__ Vt, unsigned short* __restrict__ Qn) {
  __shared__ __align__(16) unsigned short SLDS[4 * 256 * 64];  // 128 KB
  const int tid = threadIdx.x;
  const int lane = tid & 63;
  const int w = tid >> 6, wm = w >> 2, wn = w & 3;
  const int l15 = lane & 15, l4 = lane >> 4;
  const int nbx = N >> 8;
  const int bid = (int)blockIdx.x;
  const int lin = (bid & 7) * ((int)gridDim.x >> 3) + (bid >> 3);  // XCD swizzle
  const int m0 = (lin / nbx) << 8, n0 = (lin % nbx) << 8;
  const int NT = K >> 6;

  const int strow = tid >> 3, stchunk = tid & 7;
  const int schunk = stchunk ^ (strow & 7);  // pre-swizzled source chunk

  auto stage = [&](int slot, int kt) {
    unsigned short* Ad = SLDS + slot * 16384;
    unsigned short* Bd = SLDS + (2 + slot) * 16384;
#pragma unroll
    for (int i = 0; i < 4; ++i) {
      int row = i * 64 + strow;
      gload_lds16(A + (size_t)(m0 + row) * K + kt * 64 + schunk * 8,
                  Ad + row * 64 + stchunk * 8);
      gload_lds16(Bt + (size_t)(n0 + row) * K + kt * 64 + schunk * 8,
                  Bd + row * 64 + stchunk * 8);
    }
  };

  const f32x4 zero4 = {0.f, 0.f, 0.f, 0.f};
  f32x4 acc[8][4];
#pragma unroll
  for (int i = 0; i < 8; ++i)
#pragma unroll
    for (int j = 0; j < 4; ++j) acc[i][j] = zero4;

  stage(0, 0);
  __syncthreads();

  bf16x8 af[4][2], bf0[2][2], bf1[2][2];

  for (int kt = 0; kt < NT; ++kt) {
    const int s = kt & 1;
    const char* As = (const char*)(SLDS + s * 16384);
    const char* Bs = (const char*)(SLDS + (2 + s) * 16384);
    const int kp1 = (kt + 1 < NT) ? kt + 1 : NT - 1;

    stage(s ^ 1, kp1);  // prefetch next tile; drained by this iter's syncthreads

    // quadrant (mh0, nh0)
#pragma unroll
    for (int i = 0; i < 4; ++i) {
      const int ra = wm * 128 + i * 16 + l15;
#pragma unroll
      for (int kk = 0; kk < 2; ++kk)
        af[i][kk] = *(const bf16x8*)(As + ra * 128 + (((kk * 4 + l4) ^ (ra & 7)) << 4));
    }
#pragma unroll
    for (int j = 0; j < 2; ++j) {
      const int rb = wn * 64 + j * 16 + l15;
#pragma unroll
      for (int kk = 0; kk < 2; ++kk)
        bf0[j][kk] = *(const bf16x8*)(Bs + rb * 128 + (((kk * 4 + l4) ^ (rb & 7)) << 4));
    }
    __builtin_amdgcn_s_setprio(1);
#pragma unroll
    for (int i = 0; i < 4; ++i)
#pragma unroll
      for (int j = 0; j < 2; ++j)
#pragma unroll
        for (int kk = 0; kk < 2; ++kk)
          acc[i][j] = MFMA16(af[i][kk], bf0[j][kk], acc[i][j]);
    __builtin_amdgcn_s_setprio(0);

    // quadrant (mh0, nh1)
#pragma unroll
    for (int j = 0; j < 2; ++j) {
      const int rb = wn * 64 + (2 + j) * 16 + l15;
#pragma unroll
      for (int kk = 0; kk < 2; ++kk)
        bf1[j][kk] = *(const bf16x8*)(Bs + rb * 128 + (((kk * 4 + l4) ^ (rb & 7)) << 4));
    }
    __builtin_amdgcn_s_setprio(1);
#pragma unroll
    for (int i = 0; i < 4; ++i)
#pragma unroll
      for (int j = 0; j < 2; ++j)
#pragma unroll
        for (int kk = 0; kk < 2; ++kk)
          acc[i][2 + j] = MFMA16(af[i][kk], bf1[j][kk], acc[i][2 + j]);
    __builtin_amdgcn_s_setprio(0);

    // quadrant (mh1, nh1)
#pragma unroll
    for (int i = 0; i < 4; ++i) {
      const int ra = wm * 128 + (4 + i) * 16 + l15;
#pragma unroll
      for (int kk = 0; kk < 2; ++kk)
        af[i][kk] = *(const bf16x8*)(As + ra * 128 + (((kk * 4 + l4) ^ (ra & 7)) << 4));
    }
    __builtin_amdgcn_s_setprio(1);
#pragma unroll
    for (int i = 0; i < 4; ++i)
#pragma unroll
      for (int j = 0; j < 2; ++j)
#pragma unroll
        for (int kk = 0; kk < 2; ++kk)
          acc[4 + i][2 + j] = MFMA16(af[i][kk], bf1[j][kk], acc[4 + i][2 + j]);

    // quadrant (mh1, nh0) — register-only
#pragma unroll
    for (int i = 0; i < 4; ++i)
#pragma unroll
      for (int j = 0; j < 2; ++j)
#pragma unroll
        for (int kk = 0; kk < 2; ++kk)
          acc[4 + i][j] = MFMA16(af[i][kk], bf0[j][kk], acc[4 + i][j]);
    __builtin_amdgcn_s_setprio(0);

    __syncthreads();  // single sync: drains prefetch, WAR-protects both slots
  }
  // loop's final __syncthreads: all LDS reads + LDS-DMA writes drained -> LDS free

  // ---- coalesced epilogue via per-wave LDS restage (16 KB/wave) ----
  char* wbuf = reinterpret_cast<char*>(SLDS) + w * 16384;
  const int proj = n0 >> 10;                 // block-uniform (256 | 1024)
  const int nn0 = (n0 + wn * 64) & 1023;     // wave = one head
  const int hh = nn0 >> 6;
  const int mbase = m0 + wm * 128;
  const int bb = mbase >> 11;
  const float* bias = (proj == 0) ? bq : (proj == 1) ? bk : bv;
  float bcol[4];
#pragma unroll
  for (int nf = 0; nf < 4; ++nf) bcol[nf] = bias[nn0 + nf * 16 + l15];

  if (proj == 2) {
    // V: stage TRANSPOSED [d][token], XOR-swizzled 16B chunks
#pragma unroll
    for (int mf = 0; mf < 8; ++mf) {
#pragma unroll
      for (int nf = 0; nf < 4; ++nf) {
        const int d = nf * 16 + l15;
        const int tok = mf * 16 + l4 * 4;
        u32x2 pk;
        pk[0] = cvt_pk_bf16(acc[mf][nf][0] + bcol[nf], acc[mf][nf][1] + bcol[nf]);
        pk[1] = cvt_pk_bf16(acc[mf][nf][2] + bcol[nf], acc[mf][nf][3] + bcol[nf]);
        *reinterpret_cast<u32x2*>(
            wbuf + d * 256 + (((tok >> 3) ^ (d & 7)) << 4) + (tok & 7) * 2) = pk;
      }
    }
    __syncthreads();
    const size_t vbase = (size_t)(bb * 16 + hh) * 64 * 2048;
#pragma unroll
    for (int dblk = 0; dblk < 8; ++dblk) {
#pragma unroll
      for (int thalf = 0; thalf < 2; ++thalf) {
        const int d = (lane >> 3) + dblk * 8;
        const int tch = (lane & 7) + thalf * 8;
        u32x4 vv = *reinterpret_cast<const u32x4*>(
            wbuf + d * 256 + ((tch ^ (d & 7)) << 4));
        const int sidx = (mbase + tch * 8) & 2047;
        *reinterpret_cast<u32x4*>(Vt + vbase + (size_t)d * 2048 + sidx) = vv;
      }
    }
  } else {
    // Q/K: stage [token][d] (2B writes), read back 16B rows of d
    // Q path: stage q * 0.125 * log2(e)  (exp2-domain softmax fold)
#pragma unroll
    for (int mf = 0; mf < 8; ++mf) {
#pragma unroll
      for (int nf = 0; nf < 4; ++nf) {
        const int d = nf * 16 + l15;
#pragma unroll
        for (int r = 0; r < 4; ++r) {
          float v = acc[mf][nf][r] + bcol[nf];
          if (proj == 0) v *= 0.18033688f;  // (1/8) * log2(e)
          const int tok = mf * 16 + l4 * 4 + r;
          *reinterpret_cast<unsigned short*>(wbuf + tok * 128 + d * 2) = f2bf(v);
        }
      }
    }
    __syncthreads();
    const size_t t64base = (size_t)(bb * 16 + hh) * 2048;
#pragma unroll
    for (int iter = 0; iter < 16; ++iter) {
      const int tl = (lane >> 3) + iter * 8;
      const int dc = lane & 7;
      u32x4 q8 = *reinterpret_cast<const u32x4*>(wbuf + tl * 128 + dc * 16);
      const size_t t64 = t64base + ((mbase + tl) & 2047);
      if (proj == 0) {
        *reinterpret_cast<u32x4*>(Qa + t64 * 128 + dc * 8) = q8;        // q/8*log2e
        u32x4 qn = tanh8(q8, 5.54517744f);                              // tanh(q)
        *reinterpret_cast<u32x4*>(Qn + t64 * 64 + dc * 8) = qn;
      } else {
        *reinterpret_cast<u32x4*>(Ka + t64 * 128 + dc * 8) = q8;        // k
        u32x4 kn = tanh8(q8, 1.0f);                                     // tanh(k)
        *reinterpret_cast<u32x4*>(Ka + t64 * 128 + 64 + dc * 8) = kn;
      }
    }
  }
}

// ---------- Qa[:,64:128] = (lam * log2e) * tanh(Q) @ J[h] ----------
__global__ __launch_bounds__(256) void k_qnj(const unsigned short* __restrict__ Qn,
                                             const float* __restrict__ J,
                                             const float* __restrict__ lamPtr,
                                             unsigned short* __restrict__ Qa) {
  __shared__ float Jl[64 * 64];
  __shared__ float Ql[64 * 64];
  int bid = blockIdx.x;
  int bh = bid >> 5, sblk = bid & 31;
  int h = bh & 15;
  int tid = threadIdx.x;
  float lam = lamPtr[0] * 1.44269504f;   // exp2-domain fold
  const float4* Jh = reinterpret_cast<const float4*>(J + (size_t)h * 4096);
#pragma unroll
  for (int p = 0; p < 4; ++p)
    reinterpret_cast<float4*>(Jl)[p * 256 + tid] = Jh[p * 256 + tid];
  size_t tok0 = (size_t)bh * 2048 + sblk * 64;
#pragma unroll
  for (int p = 0; p < 2; ++p) {
    int idx = p * 256 + tid;
    s16x8 v = *reinterpret_cast<const s16x8*>(Qn + tok0 * 64 + idx * 8);
#pragma unroll
    for (int j = 0; j < 8; ++j) Ql[idx * 8 + j] = bf2f((unsigned short)v[j]);
  }
  __syncthreads();
  int e = tid & 63, wq = tid >> 6;
#pragma unroll 1
  for (int pass = 0; pass < 16; ++pass) {
    int tok = pass * 4 + wq;
    float a0 = 0.f, a1 = 0.f;
#pragma unroll
    for (int d = 0; d < 64; d += 2) {
      a0 += Ql[tok * 64 + d] * Jl[d * 64 + e];
      a1 += Ql[tok * 64 + d + 1] * Jl[(d + 1) * 64 + e];
    }
    Qa[(tok0 + tok) * 128 + 64 + e] = f2bf(lam * (a0 + a1));
  }
}

// ---------- causal flash attention, augmented d=128, dv=64 ----------
// R12 structure (proven 71.4us): 1024 single-qt blocks (64 q-rows), 4 waves,
// longest-first, XCD-clustered, dbuf gload_lds staging, swapped QK^T.
// NEW: exp2-domain softmax (scores pre-scaled by log2e) + T13 defer-max.
__global__ __launch_bounds__(256) void k_attn(const unsigned short* __restrict__ Qa,
                                              const unsigned short* __restrict__ Ka,
                                              const unsigned short* __restrict__ Vt,
                                              unsigned short* __restrict__ Ob) {
  constexpr int S = 2048;
  __shared__ __align__(16) unsigned short Klds[2][64 * 128];  // swizzled 256B rows
  __shared__ __align__(16) unsigned short Vtl[2][64 * 64];    // [dv][kv] swizzled

  const int blk = (int)blockIdx.x;
  const int xg = blk & 7, idx = blk >> 3;
  const int bh = xg * 4 + (idx & 3);       // 4 heads per XCD for L2 locality
  const int qt = 31 - (idx >> 2);          // descending qt: longest blocks first
  const int b = bh >> 4, h = bh & 15;
  const int tid = threadIdx.x;
  const int lane = tid & 63, w = tid >> 6;
  const int l15 = lane & 15, l4 = lane >> 4;
  const int q0 = qt * 64;
  const size_t bhS = (size_t)bh * S;
  const unsigned short* Kbase = Ka + bhS * 128;
  const unsigned short* Vbase = Vt + (size_t)bh * 64 * 2048;
  const f32x4 zero4 = {0.f, 0.f, 0.f, 0.f};

  const int rowbase = w * 16 + (lane >> 4);
  const int rb7 = rowbase & 7;
  const int cK0 = (lane & 15) ^ rb7;
  const int cK1 = cK0 ^ 4;
  const int vdvrow = w * 16 + (lane >> 3);
  const int cV = (lane & 7) ^ ((lane >> 3) & 7);

  bf16x8 qf[4];
  {
    int qrow = q0 + w * 16 + l15;
#pragma unroll
    for (int c = 0; c < 4; ++c)
      qf[c] = *reinterpret_cast<const bf16x8*>(Qa + (bhS + qrow) * 128 + c * 32 + l4 * 8);
  }

  f32x4 oacc[4];
  float m_ = -__builtin_inff(), lsum = 0.f;
#pragma unroll
  for (int v = 0; v < 4; ++v) oacc[v] = zero4;

  const int I0 = (l15 + 32 * (l4 & 1)) * 4;
  const int I1 = I0 + 64;
  const bool hi4 = (lane & 32) != 0;

#pragma unroll
  for (int p = 0; p < 4; ++p)
    gload_lds16(Kbase + (size_t)(rowbase + 4 * p) * 128 + ((p & 1) ? cK1 : cK0) * 8,
                &Klds[0][(w * 16 + p * 4) * 128]);
#pragma unroll
  for (int p = 0; p < 2; ++p)
    gload_lds16(Vbase + (size_t)(vdvrow + 8 * p) * 2048 + cV * 8,
                &Vtl[0][(w * 16 + p * 8) * 64]);
  __syncthreads();

  for (int kt = 0; kt <= qt; ++kt) {
    const int cur = kt & 1;
    const bool lastStep = (kt == qt);

    if (!lastStep) {
      const int base = (kt + 1) * 64;
      const int nxt = cur ^ 1;
#pragma unroll
      for (int p = 0; p < 4; ++p)
        gload_lds16(Kbase + (size_t)(base + rowbase + 4 * p) * 128 + ((p & 1) ? cK1 : cK0) * 8,
                    &Klds[nxt][(w * 16 + p * 4) * 128]);
#pragma unroll
      for (int p = 0; p < 2; ++p)
        gload_lds16(Vbase + (size_t)(vdvrow + 8 * p) * 2048 + base + cV * 8,
                    &Vtl[nxt][(w * 16 + p * 8) * 64]);
    }

    const char* Kl = reinterpret_cast<const char*>(Klds[cur]);
    f32x4 sc[4];
    __builtin_amdgcn_s_setprio(1);
#pragma unroll
    for (int fn = 0; fn < 4; ++fn) {
      sc[fn] = zero4;
      const int krow = fn * 16 + l15;
#pragma unroll
      for (int c = 0; c < 4; ++c) {
        bf16x8 kf = *reinterpret_cast<const bf16x8*>(
            Kl + krow * 256 + (((c * 4 + l4) ^ (krow & 7)) << 4));
        sc[fn] = MFMA16(kf, qf[c], sc[fn]);
      }
    }
    __builtin_amdgcn_s_setprio(0);

    if (lastStep) {
      const int qloc = w * 16 + l15;
#pragma unroll
      for (int fn = 0; fn < 4; ++fn)
#pragma unroll
        for (int r = 0; r < 4; ++r)
          if (fn * 16 + l4 * 4 + r > qloc) sc[fn][r] = -__builtin_inff();
    }

    // ---- online softmax in exp2 domain, with T13 defer-max
    float mx = sc[0][0];
#pragma unroll
    for (int fn = 0; fn < 4; ++fn)
#pragma unroll
      for (int r = 0; r < 4; ++r) mx = fmaxf(mx, sc[fn][r]);
    mx = fmaxf(mx, __shfl_xor(mx, 16));
    mx = fmaxf(mx, __shfl_xor(mx, 32));
    if (!__all(mx - m_ <= 11.5f)) {   // e^8 in log2 domain
      const float mn = fmaxf(m_, mx);
      const float al = exp2_(m_ - mn);
      lsum *= al;
      m_ = mn;
#pragma unroll
      for (int r = 0; r < 4; ++r) {
        float albc = __shfl(al, l4 * 4 + r);
#pragma unroll
        for (int v = 0; v < 4; ++v) oacc[v][r] *= albc;
      }
    }
    float p_[4][4];
    float rs = 0.f;
#pragma unroll
    for (int fn = 0; fn < 4; ++fn)
#pragma unroll
      for (int r = 0; r < 4; ++r) {
        float e = exp2_(sc[fn][r] - m_);
        p_[fn][r] = e;
        rs += e;
      }
    rs += __shfl_xor(rs, 16);
    rs += __shfl_xor(rs, 32);
    lsum += rs;

    unsigned cp[4][2];
#pragma unroll
    for (int fn = 0; fn < 4; ++fn) {
      cp[fn][0] = cvt_pk_bf16(p_[fn][0], p_[fn][1]);
      cp[fn][1] = cvt_pk_bf16(p_[fn][2], p_[fn][3]);
    }

    const char* Vl = reinterpret_cast<const char*>(Vtl[cur]);
#pragma unroll
    for (int c2 = 0; c2 < 2; ++c2) {
      unsigned a0 = __builtin_amdgcn_ds_bpermute(I0, (int)cp[c2 * 2][0]);
      unsigned b0 = __builtin_amdgcn_ds_bpermute(I0, (int)cp[c2 * 2 + 1][0]);
      unsigned a1 = __builtin_amdgcn_ds_bpermute(I0, (int)cp[c2 * 2][1]);
      unsigned b1 = __builtin_amdgcn_ds_bpermute(I0, (int)cp[c2 * 2 + 1][1]);
      unsigned a2 = __builtin_amdgcn_ds_bpermute(I1, (int)cp[c2 * 2][0]);
      unsigned b2 = __builtin_amdgcn_ds_bpermute(I1, (int)cp[c2 * 2 + 1][0]);
      unsigned a3 = __builtin_amdgcn_ds_bpermute(I1, (int)cp[c2 * 2][1]);
      unsigned b3 = __builtin_amdgcn_ds_bpermute(I1, (int)cp[c2 * 2 + 1][1]);
      u32x4 pw = {hi4 ? b0 : a0, hi4 ? b1 : a1, hi4 ? b2 : a2, hi4 ? b3 : a3};
      bf16x8 pa = __builtin_bit_cast(bf16x8, pw);
      __builtin_amdgcn_s_setprio(1);
#pragma unroll
      for (int v = 0; v < 4; ++v) {
        const int dvrow = v * 16 + l15;
        bf16x8 vf = *reinterpret_cast<const bf16x8*>(
            Vl + dvrow * 128 + (((c2 * 4 + l4) ^ (dvrow & 7)) << 4));
        oacc[v] = MFMA16(pa, vf, oacc[v]);
      }
      __builtin_amdgcn_s_setprio(0);
    }

    __syncthreads();
  }

  float lbc[4];
#pragma unroll
  for (int r = 0; r < 4; ++r) lbc[r] = __shfl(lsum, l4 * 4 + r);
#pragma unroll
  for (int v = 0; v < 4; ++v) {
#pragma unroll
    for (int r = 0; r < 4; ++r) {
      int row = q0 + w * 16 + l4 * 4 + r;
      float o = oacc[v][r] / lbc[r];
      Ob[((size_t)b * S + row) * 1024 + h * 64 + v * 16 + l15] = f2bf(o);
    }
  }
}

extern "C" void kernel_launch(void* const* d_in, const int* in_sizes, int n_in,
                              void* d_out, int out_size, void* d_ws, size_t ws_size,
                              hipStream_t stream) {
  const float* x   = (const float*)d_in[0];
  const float* Wq  = (const float*)d_in[1];
  const float* bq  = (const float*)d_in[2];
  const float* Wk  = (const float*)d_in[3];
  const float* bk  = (const float*)d_in[4];
  const float* Wv  = (const float*)d_in[5];
  const float* bv  = (const float*)d_in[6];
  const float* Wo  = (const float*)d_in[7];
  const float* bo  = (const float*)d_in[8];
  const float* J   = (const float*)d_in[9];
  const float* lam = (const float*)d_in[10];
  float* out = (float*)d_out;

  char* ws = (char*)d_ws;
  unsigned short* xb     = (unsigned short*)(ws);              //  8,388,608 B
  unsigned short* Wt_qkv = (unsigned short*)(ws + 8388608);    //  6,291,456 B
  unsigned short* Wt_o   = (unsigned short*)(ws + 14680064);   //  2,097,152 B
  unsigned short* Qa     = (unsigned short*)(ws + 16777216);   // 16,777,216 B
  unsigned short* Ka     = (unsigned short*)(ws + 33554432);   // 16,777,216 B
  unsigned short* Vt     = (unsigned short*)(ws + 50331648);   //  8,388,608 B
  unsigned short* Qn     = (unsigned short*)(ws + 58720256);   //  8,388,608 B
  unsigned short* Ob     = (unsigned short*)(ws + 67108864);   //  8,388,608 B

  // 1) x -> bf16
  k_f32_to_bf16<<<4096, 256, 0, stream>>>(x, xb, 1048576);

  // 2) all 4 weights -> transposed bf16 (Wt_qkv and Wt_o are adjacent in ws)
  k_transpose4_to_bf16<<<dim3(32, 32, 4), dim3(32, 8), 0, stream>>>(
      Wq, Wk, Wv, Wo, Wt_qkv);

  // 3) fused QKV projection, 256^2 2-phase + coalesced LDS-restaged epilogue
  k_gemm256_qkv<<<192, 512, 0, stream>>>(xb, Wt_qkv, 4096, 3072, 1024,
      bq, bk, bv, Qa, Ka, Vt, Qn);

  // 4) Qa[:,64:128] = (lam*log2e) * tanh(Q) @ J[h]
  k_qnj<<<1024, 256, 0, stream>>>(Qn, J, lam, Qa);

  // 5) causal flash attention (1024 single-qt blocks, longest-first; R12 grid)
  k_attn<<<1024, 256, 0, stream>>>(Qa, Ka, Vt, Ob);

  // 6) output projection + bias -> fp32 d_out (2-phase 128^2)
  k_gemm_op<<<dim3(8, 32), 256, 0, stream>>>(Ob, Wt_o, 4096, 1024, 1024,
      out, bo);
}